// Round 12
// baseline (502.343 us; speedup 1.0000x reference)
//
#include <hip/hip_runtime.h>
#include <hip/hip_bf16.h>

#define EMBED 1024
#define WINDOW 512
#define NROWS 16384  // 4 * 4096

typedef __attribute__((ext_vector_type(4))) float f32x4;
typedef __bf16 bf16x8 __attribute__((ext_vector_type(8)));

#define GLDS(g, l)                                                        \
  __builtin_amdgcn_global_load_lds(                                       \
      (const __attribute__((address_space(1))) void*)(const void*)(g),    \
      (__attribute__((address_space(3))) void*)(void*)(l), 16, 0, 0)

// ---------------- prep: fp32 -> bf16 cast, 8 elems/thread ----------------
__global__ __launch_bounds__(256) void cast_bf16_kernel(
    const float* __restrict__ in, __bf16* __restrict__ out, int n8) {
  int i = blockIdx.x * blockDim.x + threadIdx.x;
  if (i >= n8) return;
  const f32x4* p = (const f32x4*)(in + (size_t)i * 8);
  f32x4 a = p[0], b = p[1];
  bf16x8 o = {(__bf16)a[0], (__bf16)a[1], (__bf16)a[2], (__bf16)a[3],
              (__bf16)b[0], (__bf16)b[1], (__bf16)b[2], (__bf16)b[3]};
  *(bf16x8*)(out + (size_t)i * 8) = o;
}

// ---------------- prep: MB [512][1024] fp32 -> MB^T [1024][512] bf16 ------
__global__ __launch_bounds__(256) void transpose_mb_kernel(
    const float* __restrict__ mb, __bf16* __restrict__ mbt) {
  int idx = blockIdx.x * blockDim.x + threadIdx.x;  // over 512*1024
  int w = idx >> 10, d = idx & 1023;
  mbt[(size_t)d * WINDOW + w] = (__bf16)mb[idx];
}

// ============== scores + softmax + x-cast mega kernel ====================
// Identical to R11 except the B-ready wait is vmcnt(1): the xb store is the
// only vmem op younger than the B glds, so leaving 1 outstanding means "all
// B glds done" WITHOUT draining the store (the old vmcnt(0) serialized on
// the store completion every tile).
__global__ __launch_bounds__(512, 2) void scores_mega_kernel(
    const float* __restrict__ x, const __bf16* __restrict__ mbb,
    __bf16* __restrict__ xb, __bf16* __restrict__ s1) {
  __shared__ __align__(16) __bf16 ldsA[2][64 * 32];   // 8 KB
  __shared__ __align__(16) __bf16 ldsB[2][512 * 32];  // 64 KB
  __shared__ float sred[8][64];                       // 2 KB
  __shared__ float sfin[64];
  const int tid = threadIdx.x, lane = tid & 63, wave = tid >> 6;
  const int row0 = blockIdx.x * 64;  // grid 256
  const int warp_n = wave;           // cols wave*64..+63
  const int fr = lane & 15, fq = lane >> 4;

  // A reg-stage map: thread -> row tid>>3, 4 elems at (tid&7)*4
  const int arow = tid >> 3;
  const int acol4 = (tid & 7) * 4;
  const int ag = (tid >> 1) & 3;  // granule = (tid&7)>>1
  const int ah = tid & 1;         // half within granule
  const int fA = (arow & 3) ^ ((arow >> 2) & 3);
  const int aws = arow * 32 + ((ag ^ fA) * 8) + ah * 4;  // LDS elem offset
  const float* aSrc = x + (size_t)(row0 + arow) * EMBED + acol4;
  __bf16* xbDst = xb + (size_t)(row0 + arow) * EMBED + acol4;

  // B glds map: per wave 4 glds, each 16 rows x 4 granules (1024 B)
  const int srow = lane >> 2;  // 0..15
  const int sgc = (lane & 3) ^ ((lane >> 2) & 3) ^ ((lane >> 4) & 3);
  const __bf16* bSrc = mbb + (size_t)(wave * 64 + srow) * EMBED + sgc * 8;

#define STG_B(t, buf)                                                         \
  {                                                                           \
    _Pragma("unroll") for (int c = 0; c < 4; ++c)                             \
        GLDS(bSrc + (size_t)c * 16 * EMBED + (t) * 32,                        \
             &ldsB[buf][(wave * 64 + c * 16) * 32]);                          \
  }

#define PACK_WRITE(av, buf, t)                                                \
  {                                                                           \
    unsigned u0 =                                                             \
        ((unsigned)__builtin_bit_cast(unsigned short, (__bf16)av[1]) << 16) | \
        (unsigned)__builtin_bit_cast(unsigned short, (__bf16)av[0]);          \
    unsigned u1 =                                                             \
        ((unsigned)__builtin_bit_cast(unsigned short, (__bf16)av[3]) << 16) | \
        (unsigned)__builtin_bit_cast(unsigned short, (__bf16)av[2]);          \
    uint2 w2 = {u0, u1};                                                      \
    *(uint2*)(&ldsA[buf][aws]) = w2;                                          \
    *(uint2*)(xbDst + (t) * 32) = w2;                                         \
  }

#define MCOMPUTE(cur)                                                         \
  {                                                                           \
    const __bf16* As_ = &ldsA[cur][0];                                        \
    const __bf16* Bs_ = &ldsB[cur][(warp_n * 64) * 32];                       \
    const int pg_ = (fq ^ ((fr & 3) ^ ((fr >> 2) & 3))) * 8;                  \
    bf16x8 af[4], bfv[4];                                                     \
    _Pragma("unroll") for (int m = 0; m < 4; ++m)                             \
        af[m] = *(const bf16x8*)(As_ + (m * 16 + fr) * 32 + pg_);             \
    _Pragma("unroll") for (int n = 0; n < 4; ++n)                             \
        bfv[n] = *(const bf16x8*)(Bs_ + (n * 16 + fr) * 32 + pg_);            \
    asm volatile("s_waitcnt lgkmcnt(0)" ::: "memory");                        \
    __builtin_amdgcn_s_setprio(1);                                            \
    _Pragma("unroll") for (int m = 0; m < 4; ++m)                             \
        _Pragma("unroll") for (int n = 0; n < 4; ++n)                         \
            acc[m][n] = __builtin_amdgcn_mfma_f32_16x16x32_bf16(              \
                af[m], bfv[n], acc[m][n], 0, 0, 0);                           \
    __builtin_amdgcn_s_setprio(0);                                            \
  }

  f32x4 acc[4][4];
#pragma unroll
  for (int m = 0; m < 4; ++m)
#pragma unroll
    for (int n = 0; n < 4; ++n) acc[m][n] = (f32x4){0.f, 0.f, 0.f, 0.f};

  // prologue: stage tile 0
  {
    f32x4 a0 = *(const f32x4*)(aSrc);
    asm volatile("" ::: "memory");
    STG_B(0, 0);
    asm volatile("s_waitcnt vmcnt(0)" ::: "memory");
    PACK_WRITE(a0, 0, 0);
    asm volatile("s_waitcnt lgkmcnt(0)" ::: "memory");
    __builtin_amdgcn_s_barrier();
  }

  for (int t = 0; t < 32; ++t) {
    const int cur = t & 1;
    f32x4 an;
    if (t + 1 < 32) {
      an = *(const f32x4*)(aSrc + (t + 1) * 32);  // issued FIRST
      asm volatile("" ::: "memory");              // pin order vs glds
      STG_B(t + 1, cur ^ 1);
    }
    MCOMPUTE(cur);
    if (t + 1 < 32) {
      asm volatile("s_waitcnt vmcnt(4)" ::: "memory");  // A f32 arrived
      PACK_WRITE(an, cur ^ 1, t + 1);
      // B(t+1) glds done; the xb store (sole younger op) stays in flight.
      asm volatile("s_waitcnt vmcnt(1)" ::: "memory");
      asm volatile("s_waitcnt lgkmcnt(0)" ::: "memory");
    }
    __builtin_amdgcn_s_barrier();
  }
#undef STG_B
#undef PACK_WRITE
#undef MCOMPUTE

  // -------- softmax epilogue (full 512-col rows in block) ----------------
  const float scale = 0.03125f;  // 1/sqrt(1024)
  float rmx[4][4];
#pragma unroll
  for (int m = 0; m < 4; ++m)
#pragma unroll
    for (int j = 0; j < 4; ++j) {
      float v = -1e30f;
#pragma unroll
      for (int n = 0; n < 4; ++n) {
        acc[m][n][j] *= scale;
        v = fmaxf(v, acc[m][n][j]);
      }
      rmx[m][j] = v;
    }
#pragma unroll
  for (int off = 1; off < 16; off <<= 1)
#pragma unroll
    for (int m = 0; m < 4; ++m)
#pragma unroll
      for (int j = 0; j < 4; ++j)
        rmx[m][j] = fmaxf(rmx[m][j], __shfl_xor(rmx[m][j], off));
  if (fr == 0) {
#pragma unroll
    for (int m = 0; m < 4; ++m)
#pragma unroll
      for (int j = 0; j < 4; ++j) sred[warp_n][m * 16 + fq * 4 + j] = rmx[m][j];
  }
  __syncthreads();
  if (tid < 64) {
    float v = sred[0][tid];
#pragma unroll
    for (int w = 1; w < 8; ++w) v = fmaxf(v, sred[w][tid]);
    sfin[tid] = v;
  }
  __syncthreads();

  float rsm[4][4];
#pragma unroll
  for (int m = 0; m < 4; ++m)
#pragma unroll
    for (int j = 0; j < 4; ++j) {
      const float fm = sfin[m * 16 + fq * 4 + j];
      float s = 0.f;
#pragma unroll
      for (int n = 0; n < 4; ++n) {
        float e = __expf(acc[m][n][j] - fm);
        acc[m][n][j] = e;
        s += e;
      }
      rsm[m][j] = s;
    }
#pragma unroll
  for (int off = 1; off < 16; off <<= 1)
#pragma unroll
    for (int m = 0; m < 4; ++m)
#pragma unroll
      for (int j = 0; j < 4; ++j) rsm[m][j] += __shfl_xor(rsm[m][j], off);
  if (fr == 0) {
#pragma unroll
    for (int m = 0; m < 4; ++m)
#pragma unroll
      for (int j = 0; j < 4; ++j) sred[warp_n][m * 16 + fq * 4 + j] = rsm[m][j];
  }
  __syncthreads();
  if (tid < 64) {
    float v = sred[0][tid];
#pragma unroll
    for (int w = 1; w < 8; ++w) v += sred[w][tid];
    sfin[tid] = 1.0f / v;
  }
  __syncthreads();

#pragma unroll
  for (int m = 0; m < 4; ++m)
#pragma unroll
    for (int j = 0; j < 4; ++j) {
      const int row = row0 + m * 16 + fq * 4 + j;
      const float inv = sfin[m * 16 + fq * 4 + j];
#pragma unroll
      for (int n = 0; n < 4; ++n)
        s1[(size_t)row * WINDOW + warp_n * 64 + n * 16 + fr] =
            (__bf16)(acc[m][n][j] * inv);
    }
}

// ===== fused dual GEMM + blend: BK=32, ring-3 LDS (48 KB), 3 blocks/CU ===
// Same proven schedule/swizzle family, geometry retuned for TLP:
//  - LDS: 3 slots x (A 8K + B 8K) = 48 KB -> 3 blocks/CU (VGPR-bound at 12
//    waves/CU), 2-tile lookahead.
//  - Per wave per tile: 4 glds, 8 ds_read_b128 (one granule per frag),
//    16 MFMA, 2 barriers. Waits: vmcnt(8) steady (8 younger outstanding),
//    tail 4 -> 0.
//  - Swizzle (32-el rows): f(r) = (r&3)^((r>>2)&3); source granule
//    (lane&3)^f(lane>>2); read granule fq^f(fr). Exactly 8 lanes per
//    4-bank group -> conflict-free b128 (verified in mega at this layout).
// vt 0..15 retrieved (A=s1,B=mbt,K=512); vt 16..47 gate (A=xb,B=gwb,K=1024).
__global__ __launch_bounds__(256, 3) void dual_bk32r3_kernel(
    const __bf16* __restrict__ s1, const __bf16* __restrict__ xb,
    const __bf16* __restrict__ mbt, const __bf16* __restrict__ gwb,
    const float* __restrict__ gb, float* __restrict__ out) {
  __shared__ __align__(16) __bf16 ldsA[3][128 * 32];  // 24 KB
  __shared__ __align__(16) __bf16 ldsB[3][128 * 32];  // 24 KB
  const int tid = threadIdx.x, lane = tid & 63, wave = tid >> 6;
  const int bid = blockIdx.x;
  const int xcd = bid & 7;
  const int g = bid >> 3;                  // 0..127
  const int bm = xcd * 16 + (g >> 3);      // bn inner: A-panel L2 locality
  const int bn = g & 7;
  const int row0 = bm * 128, col0 = bn * 128;
  const int warp_m = wave >> 1, warp_n = wave & 1;  // 2x2 waves, 64x64 tiles
  const int fr = lane & 15, fq = lane >> 4;
  const int srow = lane >> 2;              // 0..15
  const int sgc = (lane & 3) ^ ((lane >> 2) & 3) ^ ((lane >> 4) & 3);
  const int wv32 = wave * 32;

  const __bf16* aR = s1 + (size_t)(row0 + wv32 + srow) * WINDOW + sgc * 8;
  const __bf16* bR = mbt + (size_t)(col0 + wv32 + srow) * WINDOW + sgc * 8;
  const __bf16* aG = xb + (size_t)(row0 + wv32 + srow) * EMBED + sgc * 8;
  const __bf16* bG = gwb + (size_t)(col0 + wv32 + srow) * EMBED + sgc * 8;

  // per wave per tile: 2 A-glds + 2 B-glds (16 rows x 4 granules each)
#define STG(vt, slot)                                                         \
  {                                                                           \
    if ((vt) < 16) {                                                          \
      const int k0_ = (vt)*32;                                                \
      GLDS(aR + k0_, &ldsA[slot][wv32 * 32]);                                 \
      GLDS(aR + (size_t)16 * WINDOW + k0_, &ldsA[slot][(wv32 + 16) * 32]);    \
      GLDS(bR + k0_, &ldsB[slot][wv32 * 32]);                                 \
      GLDS(bR + (size_t)16 * WINDOW + k0_, &ldsB[slot][(wv32 + 16) * 32]);    \
    } else {                                                                  \
      const int k0_ = ((vt)-16) * 32;                                         \
      GLDS(aG + k0_, &ldsA[slot][wv32 * 32]);                                 \
      GLDS(aG + (size_t)16 * EMBED + k0_, &ldsA[slot][(wv32 + 16) * 32]);     \
      GLDS(bG + k0_, &ldsB[slot][wv32 * 32]);                                 \
      GLDS(bG + (size_t)16 * EMBED + k0_, &ldsB[slot][(wv32 + 16) * 32]);     \
    }                                                                         \
  }

#define BARF                                                                  \
  {                                                                           \
    asm volatile("" ::: "memory");                                            \
    __builtin_amdgcn_s_barrier();                                             \
    asm volatile("" ::: "memory");                                            \
  }

  // one K=32 step: 4 A-frags + 4 B-frags (one b128 each), 16 MFMA
#define COMPUTE(ACC, slot)                                                    \
  {                                                                           \
    const __bf16* As_ = &ldsA[slot][(warp_m * 64 + fr) * 32];                 \
    const __bf16* Bs_ = &ldsB[slot][(warp_n * 64 + fr) * 32];                 \
    const int pg_ = (fq ^ ((fr & 3) ^ ((fr >> 2) & 3))) * 8;                  \
    bf16x8 af[4], bfv[4];                                                     \
    _Pragma("unroll") for (int m = 0; m < 4; ++m)                             \
        af[m] = *(const bf16x8*)(As_ + m * 16 * 32 + pg_);                    \
    _Pragma("unroll") for (int n = 0; n < 4; ++n)                             \
        bfv[n] = *(const bf16x8*)(Bs_ + n * 16 * 32 + pg_);                   \
    __builtin_amdgcn_s_setprio(1);                                            \
    _Pragma("unroll") for (int m = 0; m < 4; ++m)                             \
        _Pragma("unroll") for (int n = 0; n < 4; ++n)                         \
            ACC[m][n] = __builtin_amdgcn_mfma_f32_16x16x32_bf16(              \
                af[m], bfv[n], ACC[m][n], 0, 0, 0);                           \
    __builtin_amdgcn_s_setprio(0);                                            \
  }

  f32x4 accr[4][4], accg[4][4];
#pragma unroll
  for (int m = 0; m < 4; ++m)
#pragma unroll
    for (int n = 0; n < 4; ++n) {
      accr[m][n] = (f32x4){0.f, 0.f, 0.f, 0.f};
      accg[m][n] = (f32x4){0.f, 0.f, 0.f, 0.f};
    }

  const int NT = 48;  // 16 retrieved + 32 gate
  STG(0, 0);
  STG(1, 1);  // 8 loads in flight

  for (int vt = 0; vt < NT; ++vt) {
    const int slot = vt % 3;
    if (vt + 2 < NT) STG(vt + 2, (vt + 2) % 3);  // slot freed at vt-1's tail
    // wait for tile-vt's 4 loads (oldest); keep up to 8 younger in flight
    if (vt + 2 < NT) {
      asm volatile("s_waitcnt vmcnt(8)" ::: "memory");
    } else if (vt + 1 < NT) {
      asm volatile("s_waitcnt vmcnt(4)" ::: "memory");
    } else {
      asm volatile("s_waitcnt vmcnt(0)" ::: "memory");
    }
    BARF;  // all waves' tile-vt stages visible
    if (vt < 16) {
      COMPUTE(accr, slot);
    } else {
      COMPUTE(accg, slot);
    }
    BARF;  // reads of slot done before it is restaged at vt+1
  }
#undef STG
#undef COMPUTE
#undef BARF

  // epilogue: g = sigmoid(accg + gb); out = g*x + (1-g)*accr
#pragma unroll
  for (int n = 0; n < 4; ++n) {
    const int col = col0 + warp_n * 64 + n * 16 + fr;
    const float bias = gb[col];
#pragma unroll
    for (int m = 0; m < 4; ++m) {
#pragma unroll
      for (int j = 0; j < 4; ++j) {
        const int row = row0 + warp_m * 64 + m * 16 + fq * 4 + j;
        const size_t o = (size_t)row * EMBED + col;
        const float gt = 1.0f / (1.0f + __expf(-(accg[m][n][j] + bias)));
        const float xv = (float)xb[o];
        out[o] = gt * xv + (1.0f - gt) * accr[m][n][j];
      }
    }
  }
}

extern "C" void kernel_launch(void* const* d_in, const int* in_sizes, int n_in,
                              void* d_out, int out_size, void* d_ws,
                              size_t ws_size, hipStream_t stream) {
  const float* x = (const float*)d_in[0];
  const float* mb = (const float*)d_in[1];
  const float* gw = (const float*)d_in[2];
  const float* gb = (const float*)d_in[3];
  float* out = (float*)d_out;

  char* ws = (char*)d_ws;
  __bf16* xb = (__bf16*)(ws);                   // 16384*1024*2 = 33,554,432
  __bf16* mbb = (__bf16*)(ws + 33554432);       // 512*1024*2  =  1,048,576
  __bf16* mbt = (__bf16*)(ws + 34603008);       // 1024*512*2  =  1,048,576
  __bf16* gwb = (__bf16*)(ws + 35651584);       // 1024*1024*2 =  2,097,152
  __bf16* s1 = (__bf16*)(ws + 37748736);        // 16384*512*2 = 16,777,216
  // total 54,525,952 bytes

  cast_bf16_kernel<<<256, 256, 0, stream>>>(mb, mbb, 65536);
  cast_bf16_kernel<<<512, 256, 0, stream>>>(gw, gwb, 131072);
  transpose_mb_kernel<<<2048, 256, 0, stream>>>(mb, mbt);
  // scores + softmax + x-cast fused (writes xb and normalized s1)
  scores_mega_kernel<<<256, 512, 0, stream>>>(x, mbb, xb, s1);
  dual_bk32r3_kernel<<<1024, 256, 0, stream>>>(s1, xb, mbt, gwb, gb, out);
}

// Round 13
// 123.573 us; speedup vs baseline: 4.0652x; 4.0652x over previous
//
#include <hip/hip_runtime.h>
#include <hip/hip_bf16.h>

#define EMBED 1024
#define WINDOW 512
#define NROWS 16384  // 4 * 4096

typedef __attribute__((ext_vector_type(4))) float f32x4;
typedef __bf16 bf16x8 __attribute__((ext_vector_type(8)));

#define GLDS(g, l)                                                        \
  __builtin_amdgcn_global_load_lds(                                       \
      (const __attribute__((address_space(1))) void*)(const void*)(g),    \
      (__attribute__((address_space(3))) void*)(void*)(l), 16, 0, 0)

// ---------------- prep: fp32 -> bf16 cast, 8 elems/thread ----------------
__global__ __launch_bounds__(256) void cast_bf16_kernel(
    const float* __restrict__ in, __bf16* __restrict__ out, int n8) {
  int i = blockIdx.x * blockDim.x + threadIdx.x;
  if (i >= n8) return;
  const f32x4* p = (const f32x4*)(in + (size_t)i * 8);
  f32x4 a = p[0], b = p[1];
  bf16x8 o = {(__bf16)a[0], (__bf16)a[1], (__bf16)a[2], (__bf16)a[3],
              (__bf16)b[0], (__bf16)b[1], (__bf16)b[2], (__bf16)b[3]};
  *(bf16x8*)(out + (size_t)i * 8) = o;
}

// ---------------- prep: MB [512][1024] fp32 -> MB^T [1024][512] bf16 ------
__global__ __launch_bounds__(256) void transpose_mb_kernel(
    const float* __restrict__ mb, __bf16* __restrict__ mbt) {
  int idx = blockIdx.x * blockDim.x + threadIdx.x;  // over 512*1024
  int w = idx >> 10, d = idx & 1023;
  mbt[(size_t)d * WINDOW + w] = (__bf16)mb[idx];
}

// ============== scores + softmax + x-cast mega kernel ====================
// B-ready wait is vmcnt(1): the xb store is the only vmem op younger than
// the B glds, so leaving 1 outstanding means "all B glds done" WITHOUT
// draining the store.
__global__ __launch_bounds__(512, 2) void scores_mega_kernel(
    const float* __restrict__ x, const __bf16* __restrict__ mbb,
    __bf16* __restrict__ xb, __bf16* __restrict__ s1) {
  __shared__ __align__(16) __bf16 ldsA[2][64 * 32];   // 8 KB
  __shared__ __align__(16) __bf16 ldsB[2][512 * 32];  // 64 KB
  __shared__ float sred[8][64];                       // 2 KB
  __shared__ float sfin[64];
  const int tid = threadIdx.x, lane = tid & 63, wave = tid >> 6;
  const int row0 = blockIdx.x * 64;  // grid 256
  const int warp_n = wave;           // cols wave*64..+63
  const int fr = lane & 15, fq = lane >> 4;

  // A reg-stage map: thread -> row tid>>3, 4 elems at (tid&7)*4
  const int arow = tid >> 3;
  const int acol4 = (tid & 7) * 4;
  const int ag = (tid >> 1) & 3;  // granule = (tid&7)>>1
  const int ah = tid & 1;         // half within granule
  const int fA = (arow & 3) ^ ((arow >> 2) & 3);
  const int aws = arow * 32 + ((ag ^ fA) * 8) + ah * 4;  // LDS elem offset
  const float* aSrc = x + (size_t)(row0 + arow) * EMBED + acol4;
  __bf16* xbDst = xb + (size_t)(row0 + arow) * EMBED + acol4;

  // B glds map: per wave 4 glds, each 16 rows x 4 granules (1024 B)
  const int srow = lane >> 2;  // 0..15
  const int sgc = (lane & 3) ^ ((lane >> 2) & 3) ^ ((lane >> 4) & 3);
  const __bf16* bSrc = mbb + (size_t)(wave * 64 + srow) * EMBED + sgc * 8;

#define STG_B(t, buf)                                                         \
  {                                                                           \
    _Pragma("unroll") for (int c = 0; c < 4; ++c)                             \
        GLDS(bSrc + (size_t)c * 16 * EMBED + (t) * 32,                        \
             &ldsB[buf][(wave * 64 + c * 16) * 32]);                          \
  }

#define PACK_WRITE(av, buf, t)                                                \
  {                                                                           \
    unsigned u0 =                                                             \
        ((unsigned)__builtin_bit_cast(unsigned short, (__bf16)av[1]) << 16) | \
        (unsigned)__builtin_bit_cast(unsigned short, (__bf16)av[0]);          \
    unsigned u1 =                                                             \
        ((unsigned)__builtin_bit_cast(unsigned short, (__bf16)av[3]) << 16) | \
        (unsigned)__builtin_bit_cast(unsigned short, (__bf16)av[2]);          \
    uint2 w2 = {u0, u1};                                                      \
    *(uint2*)(&ldsA[buf][aws]) = w2;                                          \
    *(uint2*)(xbDst + (t) * 32) = w2;                                         \
  }

#define MCOMPUTE(cur)                                                         \
  {                                                                           \
    const __bf16* As_ = &ldsA[cur][0];                                        \
    const __bf16* Bs_ = &ldsB[cur][(warp_n * 64) * 32];                       \
    const int pg_ = (fq ^ ((fr & 3) ^ ((fr >> 2) & 3))) * 8;                  \
    bf16x8 af[4], bfv[4];                                                     \
    _Pragma("unroll") for (int m = 0; m < 4; ++m)                             \
        af[m] = *(const bf16x8*)(As_ + (m * 16 + fr) * 32 + pg_);             \
    _Pragma("unroll") for (int n = 0; n < 4; ++n)                             \
        bfv[n] = *(const bf16x8*)(Bs_ + (n * 16 + fr) * 32 + pg_);            \
    asm volatile("s_waitcnt lgkmcnt(0)" ::: "memory");                        \
    __builtin_amdgcn_s_setprio(1);                                            \
    _Pragma("unroll") for (int m = 0; m < 4; ++m)                             \
        _Pragma("unroll") for (int n = 0; n < 4; ++n)                         \
            acc[m][n] = __builtin_amdgcn_mfma_f32_16x16x32_bf16(              \
                af[m], bfv[n], acc[m][n], 0, 0, 0);                           \
    __builtin_amdgcn_s_setprio(0);                                            \
  }

  f32x4 acc[4][4];
#pragma unroll
  for (int m = 0; m < 4; ++m)
#pragma unroll
    for (int n = 0; n < 4; ++n) acc[m][n] = (f32x4){0.f, 0.f, 0.f, 0.f};

  // prologue: stage tile 0
  {
    f32x4 a0 = *(const f32x4*)(aSrc);
    asm volatile("" ::: "memory");
    STG_B(0, 0);
    asm volatile("s_waitcnt vmcnt(0)" ::: "memory");
    PACK_WRITE(a0, 0, 0);
    asm volatile("s_waitcnt lgkmcnt(0)" ::: "memory");
    __builtin_amdgcn_s_barrier();
  }

  for (int t = 0; t < 32; ++t) {
    const int cur = t & 1;
    f32x4 an;
    if (t + 1 < 32) {
      an = *(const f32x4*)(aSrc + (t + 1) * 32);  // issued FIRST
      asm volatile("" ::: "memory");              // pin order vs glds
      STG_B(t + 1, cur ^ 1);
    }
    MCOMPUTE(cur);
    if (t + 1 < 32) {
      asm volatile("s_waitcnt vmcnt(4)" ::: "memory");  // A f32 arrived
      PACK_WRITE(an, cur ^ 1, t + 1);
      // B(t+1) glds done; the xb store (sole younger op) stays in flight.
      asm volatile("s_waitcnt vmcnt(1)" ::: "memory");
      asm volatile("s_waitcnt lgkmcnt(0)" ::: "memory");
    }
    __builtin_amdgcn_s_barrier();
  }
#undef STG_B
#undef PACK_WRITE
#undef MCOMPUTE

  // -------- softmax epilogue (full 512-col rows in block) ----------------
  const float scale = 0.03125f;  // 1/sqrt(1024)
  float rmx[4][4];
#pragma unroll
  for (int m = 0; m < 4; ++m)
#pragma unroll
    for (int j = 0; j < 4; ++j) {
      float v = -1e30f;
#pragma unroll
      for (int n = 0; n < 4; ++n) {
        acc[m][n][j] *= scale;
        v = fmaxf(v, acc[m][n][j]);
      }
      rmx[m][j] = v;
    }
#pragma unroll
  for (int off = 1; off < 16; off <<= 1)
#pragma unroll
    for (int m = 0; m < 4; ++m)
#pragma unroll
      for (int j = 0; j < 4; ++j)
        rmx[m][j] = fmaxf(rmx[m][j], __shfl_xor(rmx[m][j], off));
  if (fr == 0) {
#pragma unroll
    for (int m = 0; m < 4; ++m)
#pragma unroll
      for (int j = 0; j < 4; ++j) sred[warp_n][m * 16 + fq * 4 + j] = rmx[m][j];
  }
  __syncthreads();
  if (tid < 64) {
    float v = sred[0][tid];
#pragma unroll
    for (int w = 1; w < 8; ++w) v = fmaxf(v, sred[w][tid]);
    sfin[tid] = v;
  }
  __syncthreads();

  float rsm[4][4];
#pragma unroll
  for (int m = 0; m < 4; ++m)
#pragma unroll
    for (int j = 0; j < 4; ++j) {
      const float fm = sfin[m * 16 + fq * 4 + j];
      float s = 0.f;
#pragma unroll
      for (int n = 0; n < 4; ++n) {
        float e = __expf(acc[m][n][j] - fm);
        acc[m][n][j] = e;
        s += e;
      }
      rsm[m][j] = s;
    }
#pragma unroll
  for (int off = 1; off < 16; off <<= 1)
#pragma unroll
    for (int m = 0; m < 4; ++m)
#pragma unroll
      for (int j = 0; j < 4; ++j) rsm[m][j] += __shfl_xor(rsm[m][j], off);
  if (fr == 0) {
#pragma unroll
    for (int m = 0; m < 4; ++m)
#pragma unroll
      for (int j = 0; j < 4; ++j) sred[warp_n][m * 16 + fq * 4 + j] = rsm[m][j];
  }
  __syncthreads();
  if (tid < 64) {
    float v = sred[0][tid];
#pragma unroll
    for (int w = 1; w < 8; ++w) v += sred[w][tid];
    sfin[tid] = 1.0f / v;
  }
  __syncthreads();

#pragma unroll
  for (int m = 0; m < 4; ++m)
#pragma unroll
    for (int j = 0; j < 4; ++j) {
      const int row = row0 + m * 16 + fq * 4 + j;
      const float inv = sfin[m * 16 + fq * 4 + j];
#pragma unroll
      for (int n = 0; n < 4; ++n)
        s1[(size_t)row * WINDOW + warp_n * 64 + n * 16 + fr] =
            (__bf16)(acc[m][n][j] * inv);
    }
}

// ======= fused dual GEMM + blend: 4 waves, 128x128, dbuf, 2 blocks/CU ====
// R11's proven kernel verbatim (72.7 us, MfmaUtil 28%, 0 conflicts):
// BK=64 dbuf, STG -> vmcnt(8) -> bar -> COMPUTE -> bar; 128B-row layout
// with 8-granule involution; bn-inner bijection for A-panel L2 locality.
__global__ __launch_bounds__(256, 2) void dual_fused128_kernel(
    const __bf16* __restrict__ s1, const __bf16* __restrict__ xb,
    const __bf16* __restrict__ mbt, const __bf16* __restrict__ gwb,
    const float* __restrict__ gb, float* __restrict__ out) {
  __shared__ __align__(16) __bf16 ldsA[2][128 * 64];  // 32 KB
  __shared__ __align__(16) __bf16 ldsB[2][128 * 64];  // 32 KB
  const int tid = threadIdx.x, lane = tid & 63, wave = tid >> 6;
  const int bid = blockIdx.x;
  const int xcd = bid & 7;
  const int g = bid >> 3;                  // 0..127
  const int bm = xcd * 16 + (g >> 3);      // bn inner: A-panel L2 locality
  const int bn = g & 7;
  const int row0 = bm * 128, col0 = bn * 128;
  const int warp_m = wave >> 1, warp_n = wave & 1;  // 2x2 waves, 64x64 tiles
  const int fr = lane & 15, fq = lane >> 4;
  const int srow = lane >> 3;              // 0..7
  const int sgc = (lane & 7) ^ srow;       // pre-swizzled source granule
  const int wv32 = wave * 32;

  const __bf16* aR = s1 + (size_t)(row0 + wv32 + srow) * WINDOW + sgc * 8;
  const __bf16* bR = mbt + (size_t)(col0 + wv32 + srow) * WINDOW + sgc * 8;
  const __bf16* aG = xb + (size_t)(row0 + wv32 + srow) * EMBED + sgc * 8;
  const __bf16* bG = gwb + (size_t)(col0 + wv32 + srow) * EMBED + sgc * 8;

#define STG(vt, buf)                                                          \
  {                                                                           \
    if ((vt) < 8) {                                                           \
      const int k0_ = (vt)*64;                                                \
      _Pragma("unroll") for (int c = 0; c < 4; ++c)                           \
          GLDS(aR + (size_t)c * 8 * WINDOW + k0_,                             \
               &ldsA[buf][(wv32 + c * 8) * 64]);                              \
      _Pragma("unroll") for (int c = 0; c < 4; ++c)                           \
          GLDS(bR + (size_t)c * 8 * WINDOW + k0_,                             \
               &ldsB[buf][(wv32 + c * 8) * 64]);                              \
    } else {                                                                  \
      const int k0_ = ((vt)-8) * 64;                                          \
      _Pragma("unroll") for (int c = 0; c < 4; ++c)                           \
          GLDS(aG + (size_t)c * 8 * EMBED + k0_,                              \
               &ldsA[buf][(wv32 + c * 8) * 64]);                              \
      _Pragma("unroll") for (int c = 0; c < 4; ++c)                           \
          GLDS(bG + (size_t)c * 8 * EMBED + k0_,                              \
               &ldsB[buf][(wv32 + c * 8) * 64]);                              \
    }                                                                         \
  }

#define BARF                                                                  \
  {                                                                           \
    asm volatile("" ::: "memory");                                            \
    __builtin_amdgcn_s_barrier();                                             \
    asm volatile("" ::: "memory");                                            \
  }

#define COMPUTE(ACC, cur)                                                     \
  {                                                                           \
    const __bf16* As_ = &ldsA[cur][(warp_m * 64 + fr) * 64];                  \
    const __bf16* Bs_ = &ldsB[cur][(warp_n * 64 + fr) * 64];                  \
    _Pragma("unroll") for (int kk = 0; kk < 2; ++kk) {                        \
      const int pg_ = ((kk * 4 + fq) ^ (fr & 7)) * 8;                         \
      bf16x8 af[4], bfv[4];                                                   \
      _Pragma("unroll") for (int m = 0; m < 4; ++m)                           \
          af[m] = *(const bf16x8*)(As_ + m * 16 * 64 + pg_);                  \
      _Pragma("unroll") for (int n = 0; n < 4; ++n)                           \
          bfv[n] = *(const bf16x8*)(Bs_ + n * 16 * 64 + pg_);                 \
      __builtin_amdgcn_s_setprio(1);                                          \
      _Pragma("unroll") for (int m = 0; m < 4; ++m)                           \
          _Pragma("unroll") for (int n = 0; n < 4; ++n)                       \
              ACC[m][n] = __builtin_amdgcn_mfma_f32_16x16x32_bf16(            \
                  af[m], bfv[n], ACC[m][n], 0, 0, 0);                         \
      __builtin_amdgcn_s_setprio(0);                                          \
    }                                                                         \
  }

  f32x4 accr[4][4], accg[4][4];
#pragma unroll
  for (int m = 0; m < 4; ++m)
#pragma unroll
    for (int n = 0; n < 4; ++n) {
      accr[m][n] = (f32x4){0.f, 0.f, 0.f, 0.f};
      accg[m][n] = (f32x4){0.f, 0.f, 0.f, 0.f};
    }

  STG(0, 0);
  for (int vt = 0; vt < 8; ++vt) {
    const int cur = vt & 1;
    STG(vt + 1, cur ^ 1);
    asm volatile("s_waitcnt vmcnt(8)" ::: "memory");
    BARF;
    COMPUTE(accr, cur);
    BARF;
  }
  for (int vt = 8; vt < 24; ++vt) {
    const int cur = vt & 1;
    if (vt + 1 < 24) {
      STG(vt + 1, cur ^ 1);
      asm volatile("s_waitcnt vmcnt(8)" ::: "memory");
    } else {
      asm volatile("s_waitcnt vmcnt(0)" ::: "memory");
    }
    BARF;
    COMPUTE(accg, cur);
    BARF;
  }
#undef STG
#undef COMPUTE
#undef BARF

#pragma unroll
  for (int n = 0; n < 4; ++n) {
    const int col = col0 + warp_n * 64 + n * 16 + fr;
    const float bias = gb[col];
#pragma unroll
    for (int m = 0; m < 4; ++m) {
#pragma unroll
      for (int j = 0; j < 4; ++j) {
        const int row = row0 + warp_m * 64 + m * 16 + fq * 4 + j;
        const size_t o = (size_t)row * EMBED + col;
        const float gt = 1.0f / (1.0f + __expf(-(accg[m][n][j] + bias)));
        const float xv = (float)xb[o];
        out[o] = gt * xv + (1.0f - gt) * accr[m][n][j];
      }
    }
  }
}

extern "C" void kernel_launch(void* const* d_in, const int* in_sizes, int n_in,
                              void* d_out, int out_size, void* d_ws,
                              size_t ws_size, hipStream_t stream) {
  const float* x = (const float*)d_in[0];
  const float* mb = (const float*)d_in[1];
  const float* gw = (const float*)d_in[2];
  const float* gb = (const float*)d_in[3];
  float* out = (float*)d_out;

  char* ws = (char*)d_ws;
  __bf16* xb = (__bf16*)(ws);                   // 16384*1024*2 = 33,554,432
  __bf16* mbb = (__bf16*)(ws + 33554432);       // 512*1024*2  =  1,048,576
  __bf16* mbt = (__bf16*)(ws + 34603008);       // 1024*512*2  =  1,048,576
  __bf16* gwb = (__bf16*)(ws + 35651584);       // 1024*1024*2 =  2,097,152
  __bf16* s1 = (__bf16*)(ws + 37748736);        // 16384*512*2 = 16,777,216
  // total 54,525,952 bytes

  cast_bf16_kernel<<<256, 256, 0, stream>>>(mb, mbb, 65536);
  cast_bf16_kernel<<<512, 256, 0, stream>>>(gw, gwb, 131072);
  transpose_mb_kernel<<<2048, 256, 0, stream>>>(mb, mbt);
  // scores + softmax + x-cast fused (writes xb and normalized s1)
  scores_mega_kernel<<<256, 512, 0, stream>>>(x, mbb, xb, s1);
  dual_fused128_kernel<<<1024, 256, 0, stream>>>(s1, xb, mbt, gwb, gb, out);
}

// Round 15
// 122.920 us; speedup vs baseline: 4.0867x; 1.0053x over previous
//
#include <hip/hip_runtime.h>
#include <hip/hip_bf16.h>

#define EMBED 1024
#define WINDOW 512
#define NROWS 16384  // 4 * 4096

typedef __attribute__((ext_vector_type(4))) float f32x4;
typedef __bf16 bf16x8 __attribute__((ext_vector_type(8)));

#define GLDS(g, l)                                                        \
  __builtin_amdgcn_global_load_lds(                                       \
      (const __attribute__((address_space(1))) void*)(const void*)(g),    \
      (__attribute__((address_space(3))) void*)(void*)(l), 16, 0, 0)

// ---------------- prep: fp32 -> bf16 cast, 8 elems/thread ----------------
__global__ __launch_bounds__(256) void cast_bf16_kernel(
    const float* __restrict__ in, __bf16* __restrict__ out, int n8) {
  int i = blockIdx.x * blockDim.x + threadIdx.x;
  if (i >= n8) return;
  const f32x4* p = (const f32x4*)(in + (size_t)i * 8);
  f32x4 a = p[0], b = p[1];
  bf16x8 o = {(__bf16)a[0], (__bf16)a[1], (__bf16)a[2], (__bf16)a[3],
              (__bf16)b[0], (__bf16)b[1], (__bf16)b[2], (__bf16)b[3]};
  *(bf16x8*)(out + (size_t)i * 8) = o;
}

// ------------- prep: MB [512][1024] -> MB^T [1024][512] via LDS ----------
__global__ __launch_bounds__(256) void transpose_mb_lds_kernel(
    const float* __restrict__ mb, __bf16* __restrict__ mbt) {
  __shared__ __bf16 tile[32][33];
  const int tx = threadIdx.x & 7, ty = threadIdx.x >> 3;  // 8 x 32
  const int w0 = (blockIdx.x & 15) * 32;   // 512/32 = 16
  const int d0 = (blockIdx.x >> 4) * 32;   // 1024/32 = 32 -> 512 blocks
  f32x4 v = *(const f32x4*)(mb + (size_t)(w0 + ty) * EMBED + d0 + tx * 4);
#pragma unroll
  for (int j = 0; j < 4; ++j) tile[tx * 4 + j][ty] = (__bf16)v[j];
  __syncthreads();
  unsigned u0 =
      ((unsigned)__builtin_bit_cast(unsigned short, tile[ty][tx * 4 + 1]) << 16) |
      (unsigned)__builtin_bit_cast(unsigned short, tile[ty][tx * 4 + 0]);
  unsigned u1 =
      ((unsigned)__builtin_bit_cast(unsigned short, tile[ty][tx * 4 + 3]) << 16) |
      (unsigned)__builtin_bit_cast(unsigned short, tile[ty][tx * 4 + 2]);
  uint2 w2 = {u0, u1};
  *(uint2*)(mbt + (size_t)(d0 + ty) * WINDOW + w0 + tx * 4) = w2;
}

// ============== scores + softmax + x-cast mega kernel (deep pipe) ========
// 3-ring LDS for A and B, 2-tile lookahead, ONE barrier per tile.
// Derived waits: A(t+1) ready at vmcnt(10); B(t+1) in LDS at vmcnt(7).
// Tail t=30: vmcnt(5)/vmcnt(2). t=31: none.
__global__ __launch_bounds__(512, 1) void scores_mega_kernel(
    const float* __restrict__ x, const __bf16* __restrict__ mbb,
    __bf16* __restrict__ xb, __bf16* __restrict__ s1) {
  __shared__ __align__(16) __bf16 ldsA[3][64 * 32];   // 12 KB
  __shared__ __align__(16) __bf16 ldsB[3][512 * 32];  // 96 KB
  __shared__ float sred[8][64];                       // 2 KB
  __shared__ float sfin[64];
  const int tid = threadIdx.x, lane = tid & 63, wave = tid >> 6;
  const int row0 = blockIdx.x * 64;  // grid 256
  const int warp_n = wave;           // cols wave*64..+63
  const int fr = lane & 15, fq = lane >> 4;

  // A reg-stage map: thread -> row tid>>3, 4 f32 at col (tid&7)*4
  const int arow = tid >> 3;
  const int ag = (tid >> 1) & 3;  // granule
  const int ah = tid & 1;         // half within granule
  const int fA = (arow & 3) ^ ((arow >> 2) & 3);
  const int aws = arow * 32 + ((ag ^ fA) * 8) + ah * 4;
  const float* aSrc = x + (size_t)(row0 + arow) * EMBED + (tid & 7) * 4;
  __bf16* xbDst = xb + (size_t)(row0 + arow) * EMBED + (tid & 7) * 4;

  // B glds map: per wave 4 glds, each 16 rows x 4 granules
  const int srow = lane >> 2;
  const int sgc = (lane & 3) ^ ((lane >> 2) & 3) ^ ((lane >> 4) & 3);
  const __bf16* bSrc = mbb + (size_t)(wave * 64 + srow) * EMBED + sgc * 8;

#define STG_B(t, buf)                                                         \
  {                                                                           \
    _Pragma("unroll") for (int c = 0; c < 4; ++c)                             \
        GLDS(bSrc + (size_t)c * 16 * EMBED + (t) * 32,                        \
             &ldsB[buf][(wave * 64 + c * 16) * 32]);                          \
  }

#define PACK_WRITE(av, buf, t)                                                \
  {                                                                           \
    unsigned u0 =                                                             \
        ((unsigned)__builtin_bit_cast(unsigned short, (__bf16)av[1]) << 16) | \
        (unsigned)__builtin_bit_cast(unsigned short, (__bf16)av[0]);          \
    unsigned u1 =                                                             \
        ((unsigned)__builtin_bit_cast(unsigned short, (__bf16)av[3]) << 16) | \
        (unsigned)__builtin_bit_cast(unsigned short, (__bf16)av[2]);          \
    uint2 w2 = {u0, u1};                                                      \
    *(uint2*)(&ldsA[buf][aws]) = w2;                                          \
    *(uint2*)(xbDst + (t) * 32) = w2;                                         \
  }

#define MCOMPUTE(cur)                                                         \
  {                                                                           \
    const __bf16* As_ = &ldsA[cur][0];                                        \
    const __bf16* Bs_ = &ldsB[cur][(warp_n * 64) * 32];                       \
    const int pg_ = (fq ^ ((fr & 3) ^ ((fr >> 2) & 3))) * 8;                  \
    bf16x8 af[4], bfv[4];                                                     \
    _Pragma("unroll") for (int m = 0; m < 4; ++m)                             \
        af[m] = *(const bf16x8*)(As_ + (m * 16 + fr) * 32 + pg_);             \
    _Pragma("unroll") for (int n = 0; n < 4; ++n)                             \
        bfv[n] = *(const bf16x8*)(Bs_ + (n * 16 + fr) * 32 + pg_);            \
    asm volatile("s_waitcnt lgkmcnt(0)" ::: "memory");                        \
    __builtin_amdgcn_s_setprio(1);                                            \
    _Pragma("unroll") for (int m = 0; m < 4; ++m)                             \
        _Pragma("unroll") for (int n = 0; n < 4; ++n)                         \
            acc[m][n] = __builtin_amdgcn_mfma_f32_16x16x32_bf16(              \
                af[m], bfv[n], acc[m][n], 0, 0, 0);                           \
    __builtin_amdgcn_s_setprio(0);                                            \
  }

// One tile body. APACK = A(t+1) reg (packed here); ALOAD = A(t+2) reg.
#define TBODY(t, APACK, ALOAD)                                                \
  {                                                                           \
    if ((t) + 2 < 32) {                                                       \
      ALOAD = *(const f32x4*)(aSrc + ((t) + 2) * 32);                         \
      asm volatile("" ::: "memory");                                          \
      STG_B((t) + 2, rs2);                                                    \
    }                                                                         \
    MCOMPUTE(rs0);                                                            \
    if ((t) + 1 < 32) {                                                       \
      if ((t) + 2 < 32) {                                                     \
        asm volatile("s_waitcnt vmcnt(10)" ::: "memory");                     \
      } else {                                                                \
        asm volatile("s_waitcnt vmcnt(5)" ::: "memory");                      \
      }                                                                       \
      PACK_WRITE(APACK, rs1, (t) + 1);                                        \
      if ((t) + 2 < 32) {                                                     \
        asm volatile("s_waitcnt vmcnt(7)" ::: "memory");                      \
      } else {                                                                \
        asm volatile("s_waitcnt vmcnt(2)" ::: "memory");                      \
      }                                                                       \
      asm volatile("s_waitcnt lgkmcnt(0)" ::: "memory");                      \
    }                                                                         \
    __builtin_amdgcn_s_barrier();                                             \
    const int tmp_ = rs0; rs0 = rs1; rs1 = rs2; rs2 = tmp_;                   \
  }

  f32x4 acc[4][4];
#pragma unroll
  for (int m = 0; m < 4; ++m)
#pragma unroll
    for (int n = 0; n < 4; ++n) acc[m][n] = (f32x4){0.f, 0.f, 0.f, 0.f};

  int rs0 = 0, rs1 = 1, rs2 = 2;
  f32x4 aE, aO;
  // prologue: A(0) load, B(0), A(1), B(1); wait A(0) (9 younger); pack.
  {
    f32x4 a0 = *(const f32x4*)(aSrc);
    asm volatile("" ::: "memory");
    STG_B(0, 0);
    aO = *(const f32x4*)(aSrc + 32);
    asm volatile("" ::: "memory");
    STG_B(1, 1);
    asm volatile("s_waitcnt vmcnt(9)" ::: "memory");
    PACK_WRITE(a0, 0, 0);
    asm volatile("s_waitcnt lgkmcnt(0)" ::: "memory");
    __builtin_amdgcn_s_barrier();
  }

  for (int t = 0; t < 32; t += 2) {
    TBODY(t, aO, aE);
    TBODY(t + 1, aE, aO);
  }
#undef TBODY
#undef STG_B
#undef PACK_WRITE
#undef MCOMPUTE

  // -------- softmax epilogue (full 512-col rows in block) ----------------
  const float scale = 0.03125f;  // 1/sqrt(1024)
  float rmx[4][4];
#pragma unroll
  for (int m = 0; m < 4; ++m)
#pragma unroll
    for (int j = 0; j < 4; ++j) {
      float v = -1e30f;
#pragma unroll
      for (int n = 0; n < 4; ++n) {
        acc[m][n][j] *= scale;
        v = fmaxf(v, acc[m][n][j]);
      }
      rmx[m][j] = v;
    }
#pragma unroll
  for (int off = 1; off < 16; off <<= 1)
#pragma unroll
    for (int m = 0; m < 4; ++m)
#pragma unroll
      for (int j = 0; j < 4; ++j)
        rmx[m][j] = fmaxf(rmx[m][j], __shfl_xor(rmx[m][j], off));
  if (fr == 0) {
#pragma unroll
    for (int m = 0; m < 4; ++m)
#pragma unroll
      for (int j = 0; j < 4; ++j) sred[warp_n][m * 16 + fq * 4 + j] = rmx[m][j];
  }
  __syncthreads();
  if (tid < 64) {
    float v = sred[0][tid];
#pragma unroll
    for (int w = 1; w < 8; ++w) v = fmaxf(v, sred[w][tid]);
    sfin[tid] = v;
  }
  __syncthreads();

  float rsm[4][4];
#pragma unroll
  for (int m = 0; m < 4; ++m)
#pragma unroll
    for (int j = 0; j < 4; ++j) {
      const float fm = sfin[m * 16 + fq * 4 + j];
      float s = 0.f;
#pragma unroll
      for (int n = 0; n < 4; ++n) {
        float e = __expf(acc[m][n][j] - fm);
        acc[m][n][j] = e;
        s += e;
      }
      rsm[m][j] = s;
    }
#pragma unroll
  for (int off = 1; off < 16; off <<= 1)
#pragma unroll
    for (int m = 0; m < 4; ++m)
#pragma unroll
      for (int j = 0; j < 4; ++j) rsm[m][j] += __shfl_xor(rsm[m][j], off);
  if (fr == 0) {
#pragma unroll
    for (int m = 0; m < 4; ++m)
#pragma unroll
      for (int j = 0; j < 4; ++j) sred[warp_n][m * 16 + fq * 4 + j] = rsm[m][j];
  }
  __syncthreads();
  if (tid < 64) {
    float v = sred[0][tid];
#pragma unroll
    for (int w = 1; w < 8; ++w) v += sred[w][tid];
    sfin[tid] = 1.0f / v;
  }
  __syncthreads();

#pragma unroll
  for (int m = 0; m < 4; ++m)
#pragma unroll
    for (int j = 0; j < 4; ++j) {
      const int row = row0 + m * 16 + fq * 4 + j;
      const float inv = sfin[m * 16 + fq * 4 + j];
#pragma unroll
      for (int n = 0; n < 4; ++n)
        s1[(size_t)row * WINDOW + warp_n * 64 + n * 16 + fr] =
            (__bf16)(acc[m][n][j] * inv);
    }
}

// ======= fused dual GEMM + blend: 4 waves, 128x128, dbuf, 2 blocks/CU ====
// R11/R13's proven kernel verbatim (73 us, MfmaUtil 28%, 0 conflicts).
__global__ __launch_bounds__(256, 2) void dual_fused128_kernel(
    const __bf16* __restrict__ s1, const __bf16* __restrict__ xb,
    const __bf16* __restrict__ mbt, const __bf16* __restrict__ gwb,
    const float* __restrict__ gb, float* __restrict__ out) {
  __shared__ __align__(16) __bf16 ldsA[2][128 * 64];  // 32 KB
  __shared__ __align__(16) __bf16 ldsB[2][128 * 64];  // 32 KB
  const int tid = threadIdx.x, lane = tid & 63, wave = tid >> 6;
  const int bid = blockIdx.x;
  const int xcd = bid & 7;
  const int g = bid >> 3;                  // 0..127
  const int bm = xcd * 16 + (g >> 3);      // bn inner: A-panel L2 locality
  const int bn = g & 7;
  const int row0 = bm * 128, col0 = bn * 128;
  const int warp_m = wave >> 1, warp_n = wave & 1;  // 2x2 waves, 64x64 tiles
  const int fr = lane & 15, fq = lane >> 4;
  const int srow = lane >> 3;              // 0..7
  const int sgc = (lane & 7) ^ srow;       // pre-swizzled source granule
  const int wv32 = wave * 32;

  const __bf16* aR = s1 + (size_t)(row0 + wv32 + srow) * WINDOW + sgc * 8;
  const __bf16* bR = mbt + (size_t)(col0 + wv32 + srow) * WINDOW + sgc * 8;
  const __bf16* aG = xb + (size_t)(row0 + wv32 + srow) * EMBED + sgc * 8;
  const __bf16* bG = gwb + (size_t)(col0 + wv32 + srow) * EMBED + sgc * 8;

#define STG(vt, buf)                                                          \
  {                                                                           \
    if ((vt) < 8) {                                                           \
      const int k0_ = (vt)*64;                                                \
      _Pragma("unroll") for (int c = 0; c < 4; ++c)                           \
          GLDS(aR + (size_t)c * 8 * WINDOW + k0_,                             \
               &ldsA[buf][(wv32 + c * 8) * 64]);                              \
      _Pragma("unroll") for (int c = 0; c < 4; ++c)                           \
          GLDS(bR + (size_t)c * 8 * WINDOW + k0_,                             \
               &ldsB[buf][(wv32 + c * 8) * 64]);                              \
    } else {                                                                  \
      const int k0_ = ((vt)-8) * 64;                                          \
      _Pragma("unroll") for (int c = 0; c < 4; ++c)                           \
          GLDS(aG + (size_t)c * 8 * EMBED + k0_,                              \
               &ldsA[buf][(wv32 + c * 8) * 64]);                              \
      _Pragma("unroll") for (int c = 0; c < 4; ++c)                           \
          GLDS(bG + (size_t)c * 8 * EMBED + k0_,                              \
               &ldsB[buf][(wv32 + c * 8) * 64]);                              \
    }                                                                         \
  }

#define BARF                                                                  \
  {                                                                           \
    asm volatile("" ::: "memory");                                            \
    __builtin_amdgcn_s_barrier();                                             \
    asm volatile("" ::: "memory");                                            \
  }

#define COMPUTE(ACC, cur)                                                     \
  {                                                                           \
    const __bf16* As_ = &ldsA[cur][(warp_m * 64 + fr) * 64];                  \
    const __bf16* Bs_ = &ldsB[cur][(warp_n * 64 + fr) * 64];                  \
    _Pragma("unroll") for (int kk = 0; kk < 2; ++kk) {                        \
      const int pg_ = ((kk * 4 + fq) ^ (fr & 7)) * 8;                         \
      bf16x8 af[4], bfv[4];                                                   \
      _Pragma("unroll") for (int m = 0; m < 4; ++m)                           \
          af[m] = *(const bf16x8*)(As_ + m * 16 * 64 + pg_);                  \
      _Pragma("unroll") for (int n = 0; n < 4; ++n)                           \
          bfv[n] = *(const bf16x8*)(Bs_ + n * 16 * 64 + pg_);                 \
      __builtin_amdgcn_s_setprio(1);                                          \
      _Pragma("unroll") for (int m = 0; m < 4; ++m)                           \
          _Pragma("unroll") for (int n = 0; n < 4; ++n)                       \
              ACC[m][n] = __builtin_amdgcn_mfma_f32_16x16x32_bf16(            \
                  af[m], bfv[n], ACC[m][n], 0, 0, 0);                         \
      __builtin_amdgcn_s_setprio(0);                                          \
    }                                                                         \
  }

  f32x4 accr[4][4], accg[4][4];
#pragma unroll
  for (int m = 0; m < 4; ++m)
#pragma unroll
    for (int n = 0; n < 4; ++n) {
      accr[m][n] = (f32x4){0.f, 0.f, 0.f, 0.f};
      accg[m][n] = (f32x4){0.f, 0.f, 0.f, 0.f};
    }

  STG(0, 0);
  for (int vt = 0; vt < 8; ++vt) {
    const int cur = vt & 1;
    STG(vt + 1, cur ^ 1);
    asm volatile("s_waitcnt vmcnt(8)" ::: "memory");
    BARF;
    COMPUTE(accr, cur);
    BARF;
  }
  for (int vt = 8; vt < 24; ++vt) {
    const int cur = vt & 1;
    if (vt + 1 < 24) {
      STG(vt + 1, cur ^ 1);
      asm volatile("s_waitcnt vmcnt(8)" ::: "memory");
    } else {
      asm volatile("s_waitcnt vmcnt(0)" ::: "memory");
    }
    BARF;
    COMPUTE(accg, cur);
    BARF;
  }
#undef STG
#undef COMPUTE
#undef BARF

#pragma unroll
  for (int n = 0; n < 4; ++n) {
    const int col = col0 + warp_n * 64 + n * 16 + fr;
    const float bias = gb[col];
#pragma unroll
    for (int m = 0; m < 4; ++m) {
#pragma unroll
      for (int j = 0; j < 4; ++j) {
        const int row = row0 + warp_m * 64 + m * 16 + fq * 4 + j;
        const size_t o = (size_t)row * EMBED + col;
        const float gt = 1.0f / (1.0f + __expf(-(accg[m][n][j] + bias)));
        const float xv = (float)xb[o];
        out[o] = gt * xv + (1.0f - gt) * accr[m][n][j];
      }
    }
  }
}

extern "C" void kernel_launch(void* const* d_in, const int* in_sizes, int n_in,
                              void* d_out, int out_size, void* d_ws,
                              size_t ws_size, hipStream_t stream) {
  const float* x = (const float*)d_in[0];
  const float* mb = (const float*)d_in[1];
  const float* gw = (const float*)d_in[2];
  const float* gb = (const float*)d_in[3];
  float* out = (float*)d_out;

  char* ws = (char*)d_ws;
  __bf16* xb = (__bf16*)(ws);                   // 16384*1024*2 = 33,554,432
  __bf16* mbb = (__bf16*)(ws + 33554432);       // 512*1024*2  =  1,048,576
  __bf16* mbt = (__bf16*)(ws + 34603008);       // 1024*512*2  =  1,048,576
  __bf16* gwb = (__bf16*)(ws + 35651584);       // 1024*1024*2 =  2,097,152
  __bf16* s1 = (__bf16*)(ws + 37748736);        // 16384*512*2 = 16,777,216
  // total 54,525,952 bytes

  cast_bf16_kernel<<<256, 256, 0, stream>>>(mb, mbb, 65536);
  cast_bf16_kernel<<<512, 256, 0, stream>>>(gw, gwb, 131072);
  transpose_mb_lds_kernel<<<512, 256, 0, stream>>>(mb, mbt);
  // scores + softmax + x-cast fused (writes xb and normalized s1)
  scores_mega_kernel<<<256, 512, 0, stream>>>(x, mbb, xb, s1);
  dual_fused128_kernel<<<1024, 256, 0, stream>>>(s1, xb, mbt, gwb, gb, out);
}